// Round 1
// baseline (63618.359 us; speedup 1.0000x reference)
//
#include <hip/hip_runtime.h>
#include <hip/hip_fp16.h>

typedef _Float16 h8 __attribute__((ext_vector_type(8)));
typedef _Float16 h2 __attribute__((ext_vector_type(2)));
typedef float    f4 __attribute__((ext_vector_type(4)));

#define HDIM 2048
#define FDIM 2048
#define TSEQ 4096
#define NR   8192   // 4*H rows of the fused gate matrix

__device__ __forceinline__ float sigmoidf_(float x) { return 1.0f / (1.0f + __expf(-x)); }
__device__ __forceinline__ float tanhf_(float x)    { return 1.0f - 2.0f / (1.0f + __expf(2.0f * x)); }

// ---------------------------------------------------------------------------
// GEMM: Zx[t][j] = sum_k X[t][k] * w{g}[j&2047][2048+k],  g = j>>11
// M=4096(T) x N=8192(4H) x K=2048(F), fp16 MFMA 16x16x32, 128x128 tile,
// 256 thr = 4 waves in 2x2, staging converts fp32->fp16 in regs.
// ---------------------------------------------------------------------------
__global__ __launch_bounds__(256) void gemm_zx(
    const float* __restrict__ X,
    const float* __restrict__ wfp, const float* __restrict__ wip,
    const float* __restrict__ wcp, const float* __restrict__ wop,
    _Float16* __restrict__ Zx)
{
    __shared__ __align__(16) _Float16 As[128 * 32];
    __shared__ __align__(16) _Float16 Bs[128 * 32];
    const int tid  = threadIdx.x;
    const int lane = tid & 63;
    const int wv   = tid >> 6;
    const int bm   = blockIdx.x & 31;   // 32 M-tiles
    const int bn   = blockIdx.x >> 5;   // 64 N-tiles
    const int m0 = bm * 128, n0 = bn * 128;
    const int g = n0 >> 11;             // 128-row tile never crosses a gate boundary
    const float* wsrc = (g == 0) ? wfp : (g == 1) ? wip : (g == 2) ? wcp : wop;
    const int nr0 = n0 & 2047;

    f4 acc[4][4];
    #pragma unroll
    for (int i = 0; i < 4; ++i)
        #pragma unroll
        for (int j = 0; j < 4; ++j) acc[i][j] = (f4){0.f, 0.f, 0.f, 0.f};

    const int wm = (wv >> 1) * 64, wn = (wv & 1) * 64;
    const int fr = lane & 15, kg = lane >> 4;

    for (int k0 = 0; k0 < FDIM; k0 += 32) {
        __syncthreads();
        #pragma unroll
        for (int r = 0; r < 2; ++r) {
            const int row = r * 64 + (tid >> 2);
            const int col = (tid & 3) * 8;
            const float* ax = &X[(size_t)(m0 + row) * FDIM + k0 + col];
            f4 a0 = *(const f4*)ax, a1 = *(const f4*)(ax + 4);
            h8 av = { (_Float16)a0[0], (_Float16)a0[1], (_Float16)a0[2], (_Float16)a0[3],
                      (_Float16)a1[0], (_Float16)a1[1], (_Float16)a1[2], (_Float16)a1[3] };
            *(h8*)&As[row * 32 + col] = av;
            const float* bx = &wsrc[(size_t)(nr0 + row) * 4096 + 2048 + k0 + col];
            f4 b0 = *(const f4*)bx, b1 = *(const f4*)(bx + 4);
            h8 bv = { (_Float16)b0[0], (_Float16)b0[1], (_Float16)b0[2], (_Float16)b0[3],
                      (_Float16)b1[0], (_Float16)b1[1], (_Float16)b1[2], (_Float16)b1[3] };
            *(h8*)&Bs[row * 32 + col] = bv;
        }
        __syncthreads();
        h8 af[4], bf[4];
        #pragma unroll
        for (int i = 0; i < 4; ++i) af[i] = *(const h8*)&As[(wm + i * 16 + fr) * 32 + kg * 8];
        #pragma unroll
        for (int j = 0; j < 4; ++j) bf[j] = *(const h8*)&Bs[(wn + j * 16 + fr) * 32 + kg * 8];
        #pragma unroll
        for (int i = 0; i < 4; ++i)
            #pragma unroll
            for (int j = 0; j < 4; ++j)
                acc[i][j] = __builtin_amdgcn_mfma_f32_16x16x32_f16(af[i], bf[j], acc[i][j], 0, 0, 0);
    }
    // C/D layout: col = lane&15 (N), row = (lane>>4)*4 + q (M)   [m89/m91]
    #pragma unroll
    for (int i = 0; i < 4; ++i)
        #pragma unroll
        for (int j = 0; j < 4; ++j)
            #pragma unroll
            for (int q = 0; q < 4; ++q) {
                const int row = m0 + wm + i * 16 + (lane >> 4) * 4 + q;
                const int col = n0 + wn + j * 16 + (lane & 15);
                Zx[(size_t)row * NR + col] = (_Float16)acc[i][j][q];
            }
}

// ---------------------------------------------------------------------------
// Grid barrier: monotonic counter, no reset. Requires all 256 WGs resident
// (forced: 128KiB+ dynamic LDS -> exactly 1 WG/CU on 256 CUs).
// ---------------------------------------------------------------------------
__device__ __forceinline__ void gridbar(unsigned int* cnt, unsigned int nwg, unsigned int& phase)
{
    __syncthreads();
    if (threadIdx.x == 0) {
        __hip_atomic_fetch_add(cnt, 1u, __ATOMIC_ACQ_REL, __HIP_MEMORY_SCOPE_AGENT);
        ++phase;
        const unsigned need = phase * nwg;
        while (__hip_atomic_load(cnt, __ATOMIC_ACQUIRE, __HIP_MEMORY_SCOPE_AGENT) < need)
            __builtin_amdgcn_s_sleep(1);
    }
    __syncthreads();
}

// ---------------------------------------------------------------------------
// Persistent recurrent kernel. 256 WGs x 256 thr. WG w owns h rows [8w,8w+8):
// 32 W4-rows (4 gates x 8) of the h-part weights in LDS (fp16, 128 KiB),
// interleaved layout: halfword idx = ((rl*8 + i)*32 + c)*8 + e for
// col = c*64 + i*8 + e  -> wave b128 reads are contiguous (conflict-free).
// Thread (rg=tid>>5, c=tid&31): rows rg*4..+4, cols c*64..+64.
// ---------------------------------------------------------------------------
__global__ __launch_bounds__(256, 1) void lstm_rec(
    const float* __restrict__ wfp, const float* __restrict__ wip,
    const float* __restrict__ wcp, const float* __restrict__ wop,
    const float* __restrict__ bfv, const float* __restrict__ biv,
    const float* __restrict__ bcv, const float* __restrict__ bov,
    const _Float16* __restrict__ Zx,
    _Float16* __restrict__ hbuf,      // 2 * 2048 fp16 (double buffer)
    float* __restrict__ hfin,         // 2048 fp32
    unsigned int* cnt)
{
    extern __shared__ __align__(16) char smem[];
    _Float16* Wlds = (_Float16*)smem;              // 32*2048 halves = 128 KiB
    float* z_lds = (float*)(smem + 32 * 2048 * 2); // 32 floats
    float* c_lds = z_lds + 32;                     // 8 floats

    const int tid = threadIdx.x;
    const int w   = blockIdx.x;
    const int rg  = tid >> 5, cc = tid & 31;

    // ---- one-time: load + convert + permute weights into LDS ----
    {
        const int rl = tid & 31;
        const int g = rl >> 3, r8 = rl & 7;
        const float* src = ((g == 0) ? wfp : (g == 1) ? wip : (g == 2) ? wcp : wop)
                           + (size_t)(8 * w + r8) * 4096;   // h-part cols [0,2048)
        const int cb = (tid >> 5) * 256;
        for (int col = cb; col < cb + 256; ++col) {
            const int c2 = col >> 6, ii = (col >> 3) & 7, ee = col & 7;
            Wlds[(((rl * 8 + ii) * 32 + c2) << 3) + ee] = (_Float16)src[col];
        }
    }
    float bias0 = 0.f, bias1 = 0.f, bias2 = 0.f, bias3 = 0.f;
    if (tid < 8) {
        c_lds[tid] = 0.0f;
        hbuf[8 * w + tid] = (_Float16)0.0f;   // h_0 = 0 (buffer 0)
        bias0 = bfv[8 * w + tid]; bias1 = biv[8 * w + tid];
        bias2 = bcv[8 * w + tid]; bias3 = bov[8 * w + tid];
    }
    unsigned phase = 0;
    gridbar(cnt, gridDim.x, phase);   // h_0 visible everywhere

    #pragma unroll 1
    for (int t = 0; t < TSEQ; ++t) {
        const _Float16* __restrict__ hprev = hbuf + (size_t)(t & 1) * HDIM;
        _Float16* __restrict__ hnext       = hbuf + (size_t)((t & 1) ^ 1) * HDIM;

        float zx0 = 0.f, zx1 = 0.f, zx2 = 0.f, zx3 = 0.f;
        if (tid < 8) {   // prefetch x-projection early; latency hides under dot
            const _Float16* zp = Zx + (size_t)t * NR + 8 * w + tid;
            zx0 = (float)zp[0]; zx1 = (float)zp[2048];
            zx2 = (float)zp[4096]; zx3 = (float)zp[6144];
        }
        // h chunk (64 cols) from global (4 KiB broadcast; L1/L2 serve reuse)
        h8 hv[8];
        {
            const h8* hp = (const h8*)(hprev + (size_t)cc * 64);
            #pragma unroll
            for (int i = 0; i < 8; ++i) hv[i] = hp[i];
        }
        // 4 rows x 64 cols of MACs per thread, fp32 accum via v_dot2_f32_f16
        float acc[4] = {0.f, 0.f, 0.f, 0.f};
        #pragma unroll
        for (int q = 0; q < 4; ++q) {
            const int rl = rg * 4 + q;
            const h8* wp = (const h8*)&Wlds[(size_t)((rl * 8) * 32 + cc) * 8];
            float s = 0.f;
            #pragma unroll
            for (int i = 0; i < 8; ++i) {
                h8 wv8 = wp[(size_t)i * 32];
                h8 hh  = hv[i];
                #pragma unroll
                for (int p = 0; p < 4; ++p) {
                    h2 wa = { wv8[2 * p], wv8[2 * p + 1] };
                    h2 ha = { hh[2 * p],  hh[2 * p + 1] };
                    s = __builtin_amdgcn_fdot2(wa, ha, s, false);
                }
            }
            acc[q] = s;
        }
        // reduce across the 32 col-chunk lanes (stays within 32-lane halves)
        #pragma unroll
        for (int m = 16; m >= 1; m >>= 1) {
            #pragma unroll
            for (int q = 0; q < 4; ++q) acc[q] += __shfl_xor(acc[q], m, 64);
        }
        if (cc == 0) {
            #pragma unroll
            for (int q = 0; q < 4; ++q) z_lds[rg * 4 + q] = acc[q];
        }
        __syncthreads();
        if (tid < 8) {   // finalize 8 h-elements: z rows are gate-major (g*8+r8)
            const float zf = z_lds[tid]      + zx0 + bias0;
            const float zi = z_lds[8 + tid]  + zx1 + bias1;
            const float zc = z_lds[16 + tid] + zx2 + bias2;
            const float zo = z_lds[24 + tid] + zx3 + bias3;
            const float f  = sigmoidf_(zf);
            const float i_ = sigmoidf_(zi);
            const float g_ = tanhf_(zc);
            const float o  = sigmoidf_(zo);
            const float cn = f * c_lds[tid] + i_ * g_;
            c_lds[tid] = cn;
            const float hn = o * tanhf_(cn);
            hnext[8 * w + tid] = (_Float16)hn;
            if (t == TSEQ - 1) hfin[8 * w + tid] = hn;
        }
        gridbar(cnt, gridDim.x, phase);
    }
}

// ---------------------------------------------------------------------------
// y[row] = by[row] + wy[row,:] . hfin
// ---------------------------------------------------------------------------
__global__ __launch_bounds__(256) void proj(
    const float* __restrict__ wy, const float* __restrict__ byv,
    const float* __restrict__ hfin, float* __restrict__ y)
{
    const int row = blockIdx.x;
    const float* wr = wy + (size_t)row * HDIM;
    float s = 0.f;
    for (int k = threadIdx.x * 4; k < HDIM; k += 256 * 4) {
        f4 wv = *(const f4*)&wr[k];
        f4 hv = *(const f4*)&hfin[k];
        s = fmaf(wv[0], hv[0], fmaf(wv[1], hv[1], fmaf(wv[2], hv[2], fmaf(wv[3], hv[3], s))));
    }
    #pragma unroll
    for (int m = 32; m >= 1; m >>= 1) s += __shfl_xor(s, m, 64);
    __shared__ float red[4];
    if ((threadIdx.x & 63) == 0) red[threadIdx.x >> 6] = s;
    __syncthreads();
    if (threadIdx.x == 0) y[row] = red[0] + red[1] + red[2] + red[3] + byv[row];
}

// ---------------------------------------------------------------------------
extern "C" void kernel_launch(void* const* d_in, const int* in_sizes, int n_in,
                              void* d_out, int out_size, void* d_ws, size_t ws_size,
                              hipStream_t stream)
{
    (void)in_sizes; (void)n_in; (void)out_size;
    const float* X   = (const float*)d_in[0];
    const float* wfp = (const float*)d_in[1];
    const float* bfv = (const float*)d_in[2];
    const float* wip = (const float*)d_in[3];
    const float* biv = (const float*)d_in[4];
    const float* wcp = (const float*)d_in[5];
    const float* bcv = (const float*)d_in[6];
    const float* wop = (const float*)d_in[7];
    const float* bov = (const float*)d_in[8];
    const float* wy  = (const float*)d_in[9];
    const float* byv = (const float*)d_in[10];
    float* y = (float*)d_out;

    char* ws = (char*)d_ws;
    const size_t need = ((size_t)64 << 20) + ((size_t)192 << 10);
    if (ws_size < need) return;  // fail visibly rather than corrupt

    _Float16* Zx   = (_Float16*)ws;                                   // 64 MiB
    _Float16* hbuf = (_Float16*)(ws + ((size_t)64 << 20));            // 8 KiB
    float*    hfin = (float*)(ws + ((size_t)64 << 20) + (64 << 10));  // 8 KiB
    unsigned* cnt  = (unsigned*)(ws + ((size_t)64 << 20) + (128 << 10));

    const int SMEM = 32 * 2048 * 2 + 40 * 4;  // 131232 B
    hipFuncSetAttribute(reinterpret_cast<const void*>(lstm_rec),
                        hipFuncAttributeMaxDynamicSharedMemorySize, SMEM);

    hipMemsetAsync(cnt, 0, sizeof(unsigned), stream);
    gemm_zx<<<dim3(2048), dim3(256), 0, stream>>>(X, wfp, wip, wcp, wop, Zx);
    lstm_rec<<<dim3(256), dim3(256), SMEM, stream>>>(wfp, wip, wcp, wop,
                                                     bfv, biv, bcv, bov,
                                                     Zx, hbuf, hfin, cnt);
    proj<<<dim3(2048), dim3(256), 0, stream>>>(wy, byv, hfin, y);
}

// Round 3
// 52809.460 us; speedup vs baseline: 1.2047x; 1.2047x over previous
//
#include <hip/hip_runtime.h>
#include <hip/hip_fp16.h>

typedef _Float16 h8 __attribute__((ext_vector_type(8)));
typedef _Float16 h2 __attribute__((ext_vector_type(2)));
typedef float    f4 __attribute__((ext_vector_type(4)));

#define HDIM 2048
#define FDIM 2048
#define TSEQ 4096
#define NR   8192   // 4*H rows of the fused gate matrix

__device__ __forceinline__ float sigmoidf_(float x) { return 1.0f / (1.0f + __expf(-x)); }
__device__ __forceinline__ float tanhf_(float x)    { return 1.0f - 2.0f / (1.0f + __expf(2.0f * x)); }

// ---------------------------------------------------------------------------
// GEMM: Zx[t][j] = sum_k X[t][k] * w{g}[j&2047][2048+k],  g = j>>11
// M=4096(T) x N=8192(4H) x K=2048(F), fp16 MFMA 16x16x32, 128x128 tile.
// ---------------------------------------------------------------------------
__global__ __launch_bounds__(256) void gemm_zx(
    const float* __restrict__ X,
    const float* __restrict__ wfp, const float* __restrict__ wip,
    const float* __restrict__ wcp, const float* __restrict__ wop,
    _Float16* __restrict__ Zx)
{
    __shared__ __align__(16) _Float16 As[128 * 32];
    __shared__ __align__(16) _Float16 Bs[128 * 32];
    const int tid  = threadIdx.x;
    const int lane = tid & 63;
    const int wv   = tid >> 6;
    const int bm   = blockIdx.x & 31;   // 32 M-tiles
    const int bn   = blockIdx.x >> 5;   // 64 N-tiles
    const int m0 = bm * 128, n0 = bn * 128;
    const int g = n0 >> 11;             // 128-row tile never crosses a gate boundary
    const float* wsrc = (g == 0) ? wfp : (g == 1) ? wip : (g == 2) ? wcp : wop;
    const int nr0 = n0 & 2047;

    f4 acc[4][4];
    #pragma unroll
    for (int i = 0; i < 4; ++i)
        #pragma unroll
        for (int j = 0; j < 4; ++j) acc[i][j] = (f4){0.f, 0.f, 0.f, 0.f};

    const int wm = (wv >> 1) * 64, wn = (wv & 1) * 64;
    const int fr = lane & 15, kg = lane >> 4;

    for (int k0 = 0; k0 < FDIM; k0 += 32) {
        __syncthreads();
        #pragma unroll
        for (int r = 0; r < 2; ++r) {
            const int row = r * 64 + (tid >> 2);
            const int col = (tid & 3) * 8;
            const float* ax = &X[(size_t)(m0 + row) * FDIM + k0 + col];
            f4 a0 = *(const f4*)ax, a1 = *(const f4*)(ax + 4);
            h8 av = { (_Float16)a0[0], (_Float16)a0[1], (_Float16)a0[2], (_Float16)a0[3],
                      (_Float16)a1[0], (_Float16)a1[1], (_Float16)a1[2], (_Float16)a1[3] };
            *(h8*)&As[row * 32 + col] = av;
            const float* bx = &wsrc[(size_t)(nr0 + row) * 4096 + 2048 + k0 + col];
            f4 b0 = *(const f4*)bx, b1 = *(const f4*)(bx + 4);
            h8 bv = { (_Float16)b0[0], (_Float16)b0[1], (_Float16)b0[2], (_Float16)b0[3],
                      (_Float16)b1[0], (_Float16)b1[1], (_Float16)b1[2], (_Float16)b1[3] };
            *(h8*)&Bs[row * 32 + col] = bv;
        }
        __syncthreads();
        h8 af[4], bf[4];
        #pragma unroll
        for (int i = 0; i < 4; ++i) af[i] = *(const h8*)&As[(wm + i * 16 + fr) * 32 + kg * 8];
        #pragma unroll
        for (int j = 0; j < 4; ++j) bf[j] = *(const h8*)&Bs[(wn + j * 16 + fr) * 32 + kg * 8];
        #pragma unroll
        for (int i = 0; i < 4; ++i)
            #pragma unroll
            for (int j = 0; j < 4; ++j)
                acc[i][j] = __builtin_amdgcn_mfma_f32_16x16x32_f16(af[i], bf[j], acc[i][j], 0, 0, 0);
    }
    // C/D layout: col = lane&15 (N), row = (lane>>4)*4 + q (M)   [m89/m91]
    #pragma unroll
    for (int i = 0; i < 4; ++i)
        #pragma unroll
        for (int j = 0; j < 4; ++j)
            #pragma unroll
            for (int q = 0; q < 4; ++q) {
                const int row = m0 + wm + i * 16 + (lane >> 4) * 4 + q;
                const int col = n0 + wn + j * 16 + (lane & 15);
                Zx[(size_t)row * NR + col] = (_Float16)acc[i][j][q];
            }
}

// ---------------------------------------------------------------------------
// Flag-array grid barrier (no same-address RMW serialization).
// flags[w*16] is WG w's own 64B cache line; value = monotonic phase.
// WG w release-stores its phase; all 256 threads poll one flag line each
// (relaxed, agent scope), then one agent acquire fence. Requires
// gridDim.x == blockDim.x == 256 and all WGs resident (forced by 128 KiB
// dynamic LDS -> 1 WG/CU on 256 CUs).
// ---------------------------------------------------------------------------
__device__ __forceinline__ void gridbar(unsigned int* flags, unsigned int phase)
{
    const int tid = threadIdx.x;
    __syncthreads();                      // all WG threads' stores issued & drained
    if (tid == 0) {
        __hip_atomic_store(&flags[(size_t)blockIdx.x * 16], phase,
                           __ATOMIC_RELEASE, __HIP_MEMORY_SCOPE_AGENT);
    }
    while (__hip_atomic_load(&flags[(size_t)tid * 16],
                             __ATOMIC_RELAXED, __HIP_MEMORY_SCOPE_AGENT) < phase)
        __builtin_amdgcn_s_sleep(1);
    __syncthreads();
    __builtin_amdgcn_fence(__ATOMIC_ACQUIRE, "agent");
}

// ---------------------------------------------------------------------------
// Persistent recurrent kernel. 256 WGs x 256 thr. WG w owns h rows [8w,8w+8):
// 32 W4-rows (4 gates x 8) of the h-part weights in LDS (fp16, 128 KiB),
// interleaved layout: halfword idx = ((rl*8 + i)*32 + c)*8 + e for
// col = c*64 + i*8 + e  -> wave b128 reads are contiguous (conflict-free).
// Thread (rg=tid>>5, c=tid&31): rows rg*4..+4, cols c*64..+64.
// ---------------------------------------------------------------------------
__global__ __launch_bounds__(256, 1) void lstm_rec(
    const float* __restrict__ wfp, const float* __restrict__ wip,
    const float* __restrict__ wcp, const float* __restrict__ wop,
    const float* __restrict__ bfv, const float* __restrict__ biv,
    const float* __restrict__ bcv, const float* __restrict__ bov,
    const _Float16* __restrict__ Zx,
    _Float16* __restrict__ hbuf,      // 2 * 2048 fp16 (double buffer)
    float* __restrict__ hfin,         // 2048 fp32
    unsigned int* flags)
{
    extern __shared__ __align__(16) char smem[];
    _Float16* Wlds = (_Float16*)smem;              // 32*2048 halves = 128 KiB
    float* z_lds = (float*)(smem + 32 * 2048 * 2); // 32 floats
    float* c_lds = z_lds + 32;                     // 8 floats

    const int tid = threadIdx.x;
    const int w   = blockIdx.x;
    const int rg  = tid >> 5, cc = tid & 31;

    // ---- one-time: load + convert + permute weights into LDS ----
    {
        const int rl = tid & 31;
        const int g = rl >> 3, r8 = rl & 7;
        const float* src = ((g == 0) ? wfp : (g == 1) ? wip : (g == 2) ? wcp : wop)
                           + (size_t)(8 * w + r8) * 4096;   // h-part cols [0,2048)
        const int cb = (tid >> 5) * 256;
        for (int col = cb; col < cb + 256; ++col) {
            const int c2 = col >> 6, ii = (col >> 3) & 7, ee = col & 7;
            Wlds[(((rl * 8 + ii) * 32 + c2) << 3) + ee] = (_Float16)src[col];
        }
    }
    float bias0 = 0.f, bias1 = 0.f, bias2 = 0.f, bias3 = 0.f;
    if (tid < 8) {
        c_lds[tid] = 0.0f;
        hbuf[8 * w + tid] = (_Float16)0.0f;   // h_0 = 0 (buffer 0)
        bias0 = bfv[8 * w + tid]; bias1 = biv[8 * w + tid];
        bias2 = bcv[8 * w + tid]; bias3 = bov[8 * w + tid];
    }
    gridbar(flags, 1u);   // h_0 visible everywhere

    #pragma unroll 1
    for (int t = 0; t < TSEQ; ++t) {
        const _Float16* __restrict__ hprev = hbuf + (size_t)(t & 1) * HDIM;
        _Float16* __restrict__ hnext       = hbuf + (size_t)((t & 1) ^ 1) * HDIM;

        float zx0 = 0.f, zx1 = 0.f, zx2 = 0.f, zx3 = 0.f;
        if (tid < 8) {   // prefetch x-projection early; latency hides under dot
            const _Float16* zp = Zx + (size_t)t * NR + 8 * w + tid;
            zx0 = (float)zp[0]; zx1 = (float)zp[2048];
            zx2 = (float)zp[4096]; zx3 = (float)zp[6144];
        }
        // h chunk (64 cols) from global (4 KiB broadcast; L1/L2 serve reuse)
        h8 hv[8];
        {
            const h8* hp = (const h8*)(hprev + (size_t)cc * 64);
            #pragma unroll
            for (int i = 0; i < 8; ++i) hv[i] = hp[i];
        }
        // 4 rows x 64 cols of MACs per thread, fp32 accum via v_dot2_f32_f16
        float acc[4] = {0.f, 0.f, 0.f, 0.f};
        #pragma unroll
        for (int q = 0; q < 4; ++q) {
            const int rl = rg * 4 + q;
            const h8* wp = (const h8*)&Wlds[(size_t)((rl * 8) * 32 + cc) * 8];
            float s = 0.f;
            #pragma unroll
            for (int i = 0; i < 8; ++i) {
                h8 wv8 = wp[(size_t)i * 32];
                h8 hh  = hv[i];
                #pragma unroll
                for (int p = 0; p < 4; ++p) {
                    h2 wa = { wv8[2 * p], wv8[2 * p + 1] };
                    h2 ha = { hh[2 * p],  hh[2 * p + 1] };
                    s = __builtin_amdgcn_fdot2(wa, ha, s, false);
                }
            }
            acc[q] = s;
        }
        // reduce across the 32 col-chunk lanes (stays within 32-lane halves)
        #pragma unroll
        for (int m = 16; m >= 1; m >>= 1) {
            #pragma unroll
            for (int q = 0; q < 4; ++q) acc[q] += __shfl_xor(acc[q], m, 64);
        }
        if (cc == 0) {
            #pragma unroll
            for (int q = 0; q < 4; ++q) z_lds[rg * 4 + q] = acc[q];
        }
        __syncthreads();
        if (tid < 8) {   // finalize 8 h-elements: z rows are gate-major (g*8+r8)
            const float zf = z_lds[tid]      + zx0 + bias0;
            const float zi = z_lds[8 + tid]  + zx1 + bias1;
            const float zc = z_lds[16 + tid] + zx2 + bias2;
            const float zo = z_lds[24 + tid] + zx3 + bias3;
            const float f  = sigmoidf_(zf);
            const float i_ = sigmoidf_(zi);
            const float g_ = tanhf_(zc);
            const float o  = sigmoidf_(zo);
            const float cn = f * c_lds[tid] + i_ * g_;
            c_lds[tid] = cn;
            const float hn = o * tanhf_(cn);
            hnext[8 * w + tid] = (_Float16)hn;
            if (t == TSEQ - 1) hfin[8 * w + tid] = hn;
        }
        gridbar(flags, (unsigned)t + 2u);
    }
}

// ---------------------------------------------------------------------------
// y[row] = by[row] + wy[row,:] . hfin
// ---------------------------------------------------------------------------
__global__ __launch_bounds__(256) void proj(
    const float* __restrict__ wy, const float* __restrict__ byv,
    const float* __restrict__ hfin, float* __restrict__ y)
{
    const int row = blockIdx.x;
    const float* wr = wy + (size_t)row * HDIM;
    float s = 0.f;
    for (int k = threadIdx.x * 4; k < HDIM; k += 256 * 4) {
        f4 wv = *(const f4*)&wr[k];
        f4 hv = *(const f4*)&hfin[k];
        s = fmaf(wv[0], hv[0], fmaf(wv[1], hv[1], fmaf(wv[2], hv[2], fmaf(wv[3], hv[3], s))));
    }
    #pragma unroll
    for (int m = 32; m >= 1; m >>= 1) s += __shfl_xor(s, m, 64);
    __shared__ float red[4];
    if ((threadIdx.x & 63) == 0) red[threadIdx.x >> 6] = s;
    __syncthreads();
    if (threadIdx.x == 0) y[row] = red[0] + red[1] + red[2] + red[3] + byv[row];
}

// ---------------------------------------------------------------------------
extern "C" void kernel_launch(void* const* d_in, const int* in_sizes, int n_in,
                              void* d_out, int out_size, void* d_ws, size_t ws_size,
                              hipStream_t stream)
{
    (void)in_sizes; (void)n_in; (void)out_size;
    const float* X   = (const float*)d_in[0];
    const float* wfp = (const float*)d_in[1];
    const float* bfv = (const float*)d_in[2];
    const float* wip = (const float*)d_in[3];
    const float* biv = (const float*)d_in[4];
    const float* wcp = (const float*)d_in[5];
    const float* bcv = (const float*)d_in[6];
    const float* wop = (const float*)d_in[7];
    const float* bov = (const float*)d_in[8];
    const float* wy  = (const float*)d_in[9];
    const float* byv = (const float*)d_in[10];
    float* y = (float*)d_out;

    char* ws = (char*)d_ws;
    const size_t need = ((size_t)64 << 20) + ((size_t)256 << 10);
    if (ws_size < need) return;  // fail visibly rather than corrupt

    _Float16* Zx   = (_Float16*)ws;                                    // 64 MiB
    _Float16* hbuf = (_Float16*)(ws + ((size_t)64 << 20));             // 8 KiB
    float*    hfin = (float*)(ws + ((size_t)64 << 20) + (64 << 10));   // 8 KiB
    unsigned* flags = (unsigned*)(ws + ((size_t)64 << 20) + (128 << 10)); // 16 KiB (256 x 64B)

    const int SMEM = 32 * 2048 * 2 + 40 * 4;  // 131232 B
    (void)hipFuncSetAttribute(reinterpret_cast<const void*>(lstm_rec),
                              hipFuncAttributeMaxDynamicSharedMemorySize, SMEM);

    (void)hipMemsetAsync(flags, 0, 256 * 64, stream);
    gemm_zx<<<dim3(2048), dim3(256), 0, stream>>>(X, wfp, wip, wcp, wop, Zx);
    lstm_rec<<<dim3(256), dim3(256), SMEM, stream>>>(wfp, wip, wcp, wop,
                                                     bfv, biv, bcv, bov,
                                                     Zx, hbuf, hfin, flags);
    proj<<<dim3(2048), dim3(256), 0, stream>>>(wy, byv, hfin, y);
}

// Round 4
// 13860.500 us; speedup vs baseline: 4.5899x; 3.8101x over previous
//
#include <hip/hip_runtime.h>
#include <hip/hip_fp16.h>

typedef _Float16 h8 __attribute__((ext_vector_type(8)));
typedef _Float16 h2 __attribute__((ext_vector_type(2)));
typedef float    f4 __attribute__((ext_vector_type(4)));
typedef unsigned int u32;
typedef u32 u32x4 __attribute__((ext_vector_type(4)));

#define HDIM 2048
#define FDIM 2048
#define TSEQ 4096
#define NR   8192   // 4*H rows of the fused gate matrix

__device__ __forceinline__ float sigmoidf_(float x) { return 1.0f / (1.0f + __expf(-x)); }
__device__ __forceinline__ float tanhf_(float x)    { return 1.0f - 2.0f / (1.0f + __expf(2.0f * x)); }

// Bank-swizzle for the LDS h-stage: 16B groups, low4 of group idx XOR'd with
// the chunk idx -> read pattern (fixed i, varying cc) spreads over 8 banks
// (4-way conflict instead of 32-way).
__device__ __forceinline__ int swz(int g) { return (g & ~15) | ((g ^ (g >> 4)) & 15); }

// ---------------------------------------------------------------------------
// GEMM: Zx[t][j] = sum_k X[t][k] * w{g}[j&2047][2048+k],  g = j>>11
// M=4096(T) x N=8192(4H) x K=2048(F), fp16 MFMA 16x16x32, 128x128 tile.
// ---------------------------------------------------------------------------
__global__ __launch_bounds__(256) void gemm_zx(
    const float* __restrict__ X,
    const float* __restrict__ wfp, const float* __restrict__ wip,
    const float* __restrict__ wcp, const float* __restrict__ wop,
    _Float16* __restrict__ Zx)
{
    __shared__ __align__(16) _Float16 As[128 * 32];
    __shared__ __align__(16) _Float16 Bs[128 * 32];
    const int tid  = threadIdx.x;
    const int lane = tid & 63;
    const int wv   = tid >> 6;
    const int bm   = blockIdx.x & 31;   // 32 M-tiles
    const int bn   = blockIdx.x >> 5;   // 64 N-tiles
    const int m0 = bm * 128, n0 = bn * 128;
    const int g = n0 >> 11;             // 128-row tile never crosses a gate boundary
    const float* wsrc = (g == 0) ? wfp : (g == 1) ? wip : (g == 2) ? wcp : wop;
    const int nr0 = n0 & 2047;

    f4 acc[4][4];
    #pragma unroll
    for (int i = 0; i < 4; ++i)
        #pragma unroll
        for (int j = 0; j < 4; ++j) acc[i][j] = (f4){0.f, 0.f, 0.f, 0.f};

    const int wm = (wv >> 1) * 64, wn = (wv & 1) * 64;
    const int fr = lane & 15, kg = lane >> 4;

    for (int k0 = 0; k0 < FDIM; k0 += 32) {
        __syncthreads();
        #pragma unroll
        for (int r = 0; r < 2; ++r) {
            const int row = r * 64 + (tid >> 2);
            const int col = (tid & 3) * 8;
            const float* ax = &X[(size_t)(m0 + row) * FDIM + k0 + col];
            f4 a0 = *(const f4*)ax, a1 = *(const f4*)(ax + 4);
            h8 av = { (_Float16)a0[0], (_Float16)a0[1], (_Float16)a0[2], (_Float16)a0[3],
                      (_Float16)a1[0], (_Float16)a1[1], (_Float16)a1[2], (_Float16)a1[3] };
            *(h8*)&As[row * 32 + col] = av;
            const float* bx = &wsrc[(size_t)(nr0 + row) * 4096 + 2048 + k0 + col];
            f4 b0 = *(const f4*)bx, b1 = *(const f4*)(bx + 4);
            h8 bv = { (_Float16)b0[0], (_Float16)b0[1], (_Float16)b0[2], (_Float16)b0[3],
                      (_Float16)b1[0], (_Float16)b1[1], (_Float16)b1[2], (_Float16)b1[3] };
            *(h8*)&Bs[row * 32 + col] = bv;
        }
        __syncthreads();
        h8 af[4], bf[4];
        #pragma unroll
        for (int i = 0; i < 4; ++i) af[i] = *(const h8*)&As[(wm + i * 16 + fr) * 32 + kg * 8];
        #pragma unroll
        for (int j = 0; j < 4; ++j) bf[j] = *(const h8*)&Bs[(wn + j * 16 + fr) * 32 + kg * 8];
        #pragma unroll
        for (int i = 0; i < 4; ++i)
            #pragma unroll
            for (int j = 0; j < 4; ++j)
                acc[i][j] = __builtin_amdgcn_mfma_f32_16x16x32_f16(af[i], bf[j], acc[i][j], 0, 0, 0);
    }
    // C/D layout: col = lane&15 (N), row = (lane>>4)*4 + q (M)   [m89/m91]
    #pragma unroll
    for (int i = 0; i < 4; ++i)
        #pragma unroll
        for (int j = 0; j < 4; ++j)
            #pragma unroll
            for (int q = 0; q < 4; ++q) {
                const int row = m0 + wm + i * 16 + (lane >> 4) * 4 + q;
                const int col = n0 + wn + j * 16 + (lane & 15);
                Zx[(size_t)row * NR + col] = (_Float16)acc[i][j][q];
            }
}

// ---------------------------------------------------------------------------
// Persistent recurrent kernel, fence-free tag-in-word messaging.
// hword: 2 slots x 2048 u32. word j of slot (t&1) = (t<<16) | fp16bits(h_t[j]).
// Writers: global_store_dword sc0 sc1 (coherence point, no fence).
// Readers: global_load_dwordx4 sc0 sc1 poll until tag==t, stage to LDS.
// The tag-poll IS the grid barrier (2-slot ring safety: a writer reaches
// tag t+2 on a slot only after all WGs published t+1, which required them
// to have fully consumed t). hword is memset to 0 per launch: slot0 then
// holds (tag=0, h=0) == the correct h_0, and no cross-replay tag aliasing.
// ---------------------------------------------------------------------------
__global__ __launch_bounds__(256, 1) void lstm_rec(
    const float* __restrict__ wfp, const float* __restrict__ wip,
    const float* __restrict__ wcp, const float* __restrict__ wop,
    const float* __restrict__ bfv, const float* __restrict__ biv,
    const float* __restrict__ bcv, const float* __restrict__ bov,
    const _Float16* __restrict__ Zx,
    u32* __restrict__ hword,          // 2 * 2048 tagged words
    float* __restrict__ hfin)         // 2048 fp32
{
    extern __shared__ __align__(16) char smem[];
    _Float16* Wlds = (_Float16*)smem;                       // 128 KiB weights
    u32* stage = (u32*)(smem + 32 * 2048 * 2);              // 8 KiB h stage
    float* z_lds = (float*)(smem + 32 * 2048 * 2 + 8192);   // 32 floats
    float* c_lds = z_lds + 32;                              // 8 floats

    const int tid = threadIdx.x;
    const int w   = blockIdx.x;
    const int rg  = tid >> 5, cc = tid & 31;

    // ---- one-time: load + convert + permute weights into LDS ----
    {
        const int rl = tid & 31;
        const int g = rl >> 3, r8 = rl & 7;
        const float* src = ((g == 0) ? wfp : (g == 1) ? wip : (g == 2) ? wcp : wop)
                           + (size_t)(8 * w + r8) * 4096;   // h-part cols [0,2048)
        const int cb = (tid >> 5) * 256;
        for (int col = cb; col < cb + 256; ++col) {
            const int c2 = col >> 6, ii = (col >> 3) & 7, ee = col & 7;
            Wlds[(((rl * 8 + ii) * 32 + c2) << 3) + ee] = (_Float16)src[col];
        }
    }
    float bias0 = 0.f, bias1 = 0.f, bias2 = 0.f, bias3 = 0.f;
    if (tid < 8) {
        c_lds[tid] = 0.0f;
        bias0 = bfv[8 * w + tid]; bias1 = biv[8 * w + tid];
        bias2 = bcv[8 * w + tid]; bias3 = bov[8 * w + tid];
    }
    __syncthreads();   // weights + c ready (WG-local; no grid barrier needed)

    #pragma unroll 1
    for (int t = 0; t < TSEQ; ++t) {
        float zx0 = 0.f, zx1 = 0.f, zx2 = 0.f, zx3 = 0.f;
        if (tid < 8) {   // x-projection prefetch (plain loads, L2-warm stream)
            const _Float16* zp = Zx + (size_t)t * NR + 8 * w + tid;
            zx0 = (float)zp[0]; zx1 = (float)zp[2048];
            zx2 = (float)zp[4096]; zx3 = (float)zp[6144];
        }

        // ---- poll own 8 tagged words of h_t (slot t&1) at coherence point ----
        const u32* p = hword + (size_t)(t & 1) * HDIM + tid * 8;
        const u32 texp = (u32)t << 16;
        u32x4 A, B;
        for (;;) {
            asm volatile(
                "global_load_dwordx4 %0, %2, off sc0 sc1\n\t"
                "global_load_dwordx4 %1, %2, off offset:16 sc0 sc1\n\t"
                "s_waitcnt vmcnt(0)"
                : "=&v"(A), "=&v"(B) : "v"(p) : "memory");
            const u32 bad = ((A.x ^ texp) | (A.y ^ texp) | (A.z ^ texp) | (A.w ^ texp) |
                             (B.x ^ texp) | (B.y ^ texp) | (B.z ^ texp) | (B.w ^ texp))
                            & 0xFFFF0000u;
            if (!bad) break;
            __builtin_amdgcn_s_sleep(1);
        }
        // stage the 8 fresh words (2 swizzled 16B groups) for WG-wide reuse
        *(u32x4*)&stage[swz(tid * 2) * 4]     = A;
        *(u32x4*)&stage[swz(tid * 2 + 1) * 4] = B;
        __syncthreads();

        // ---- unpack this thread's 64 h values (cols cc*64..+64) from LDS ----
        h2 hh[8][4];
        #pragma unroll
        for (int i = 0; i < 8; ++i) {
            u32x4 ga = *(const u32x4*)&stage[swz(cc * 16 + 2 * i) * 4];
            u32x4 gb = *(const u32x4*)&stage[swz(cc * 16 + 2 * i + 1) * 4];
            hh[i][0] = __builtin_bit_cast(h2, (u32)((ga.x & 0xffffu) | (ga.y << 16)));
            hh[i][1] = __builtin_bit_cast(h2, (u32)((ga.z & 0xffffu) | (ga.w << 16)));
            hh[i][2] = __builtin_bit_cast(h2, (u32)((gb.x & 0xffffu) | (gb.y << 16)));
            hh[i][3] = __builtin_bit_cast(h2, (u32)((gb.z & 0xffffu) | (gb.w << 16)));
        }

        // ---- 4 rows x 64 cols of MACs per thread, fp32 accum via fdot2 ----
        float acc[4];
        #pragma unroll
        for (int q = 0; q < 4; ++q) {
            const int rl = rg * 4 + q;
            const h8* wp = (const h8*)&Wlds[(size_t)((rl * 8) * 32 + cc) * 8];
            float s = 0.f;
            #pragma unroll
            for (int i = 0; i < 8; ++i) {
                h8 wv8 = wp[(size_t)i * 32];
                #pragma unroll
                for (int pp = 0; pp < 4; ++pp) {
                    h2 wa = { wv8[2 * pp], wv8[2 * pp + 1] };
                    s = __builtin_amdgcn_fdot2(wa, hh[i][pp], s, false);
                }
            }
            acc[q] = s;
        }
        // reduce across the 32 col-chunk lanes (stays within 32-lane halves)
        #pragma unroll
        for (int m = 16; m >= 1; m >>= 1) {
            #pragma unroll
            for (int q = 0; q < 4; ++q) acc[q] += __shfl_xor(acc[q], m, 64);
        }
        if (cc == 0) {
            #pragma unroll
            for (int q = 0; q < 4; ++q) z_lds[rg * 4 + q] = acc[q];
        }
        __syncthreads();
        if (tid < 8) {   // finalize 8 h-elements; publish tagged words for t+1
            const float zf = z_lds[tid]      + zx0 + bias0;
            const float zi = z_lds[8 + tid]  + zx1 + bias1;
            const float zc = z_lds[16 + tid] + zx2 + bias2;
            const float zo = z_lds[24 + tid] + zx3 + bias3;
            const float f  = sigmoidf_(zf);
            const float i_ = sigmoidf_(zi);
            const float g_ = tanhf_(zc);
            const float o  = sigmoidf_(zo);
            const float cn = f * c_lds[tid] + i_ * g_;
            c_lds[tid] = cn;
            const float hn = o * tanhf_(cn);
            const unsigned short hb =
                __builtin_bit_cast(unsigned short, (_Float16)hn);
            const u32 word = ((u32)(t + 1) << 16) | (u32)hb;
            u32* op = hword + (size_t)((t + 1) & 1) * HDIM + 8 * w + tid;
            asm volatile("global_store_dword %0, %1, off sc0 sc1"
                         :: "v"(op), "v"(word) : "memory");
            if (t == TSEQ - 1) hfin[8 * w + tid] = hn;
        }
    }
}

// ---------------------------------------------------------------------------
// y[row] = by[row] + wy[row,:] . hfin
// ---------------------------------------------------------------------------
__global__ __launch_bounds__(256) void proj(
    const float* __restrict__ wy, const float* __restrict__ byv,
    const float* __restrict__ hfin, float* __restrict__ y)
{
    const int row = blockIdx.x;
    const float* wr = wy + (size_t)row * HDIM;
    float s = 0.f;
    for (int k = threadIdx.x * 4; k < HDIM; k += 256 * 4) {
        f4 wv = *(const f4*)&wr[k];
        f4 hv = *(const f4*)&hfin[k];
        s = fmaf(wv[0], hv[0], fmaf(wv[1], hv[1], fmaf(wv[2], hv[2], fmaf(wv[3], hv[3], s))));
    }
    #pragma unroll
    for (int m = 32; m >= 1; m >>= 1) s += __shfl_xor(s, m, 64);
    __shared__ float red[4];
    if ((threadIdx.x & 63) == 0) red[threadIdx.x >> 6] = s;
    __syncthreads();
    if (threadIdx.x == 0) y[row] = red[0] + red[1] + red[2] + red[3] + byv[row];
}

// ---------------------------------------------------------------------------
extern "C" void kernel_launch(void* const* d_in, const int* in_sizes, int n_in,
                              void* d_out, int out_size, void* d_ws, size_t ws_size,
                              hipStream_t stream)
{
    (void)in_sizes; (void)n_in; (void)out_size;
    const float* X   = (const float*)d_in[0];
    const float* wfp = (const float*)d_in[1];
    const float* bfv = (const float*)d_in[2];
    const float* wip = (const float*)d_in[3];
    const float* biv = (const float*)d_in[4];
    const float* wcp = (const float*)d_in[5];
    const float* bcv = (const float*)d_in[6];
    const float* wop = (const float*)d_in[7];
    const float* bov = (const float*)d_in[8];
    const float* wy  = (const float*)d_in[9];
    const float* byv = (const float*)d_in[10];
    float* y = (float*)d_out;

    char* ws = (char*)d_ws;
    const size_t need = ((size_t)64 << 20) + ((size_t)64 << 10);
    if (ws_size < need) return;  // fail visibly rather than corrupt

    _Float16* Zx  = (_Float16*)ws;                                   // 64 MiB
    u32* hword    = (u32*)(ws + ((size_t)64 << 20));                 // 16 KiB
    float* hfin   = (float*)(ws + ((size_t)64 << 20) + (16 << 10));  // 8 KiB

    const int SMEM = 32 * 2048 * 2 + 8192 + 40 * 4;  // 139424 B
    (void)hipFuncSetAttribute(reinterpret_cast<const void*>(lstm_rec),
                              hipFuncAttributeMaxDynamicSharedMemorySize, SMEM);

    // slot0 = (tag 0, h=0) == correct h_0; also kills cross-replay tag aliasing
    (void)hipMemsetAsync(hword, 0, 2 * HDIM * sizeof(u32), stream);
    gemm_zx<<<dim3(2048), dim3(256), 0, stream>>>(X, wfp, wip, wcp, wop, Zx);
    lstm_rec<<<dim3(256), dim3(256), SMEM, stream>>>(wfp, wip, wcp, wop,
                                                     bfv, biv, bcv, bov,
                                                     Zx, hword, hfin);
    proj<<<dim3(2048), dim3(256), 0, stream>>>(wy, byv, hfin, y);
}

// Round 6
// 12064.513 us; speedup vs baseline: 5.2732x; 1.1489x over previous
//
#include <hip/hip_runtime.h>
#include <hip/hip_fp16.h>

typedef _Float16 h8 __attribute__((ext_vector_type(8)));
typedef _Float16 h2 __attribute__((ext_vector_type(2)));
typedef float    f4 __attribute__((ext_vector_type(4)));
typedef unsigned int u32;
typedef u32 u32x4 __attribute__((ext_vector_type(4)));

#define HDIM 2048
#define FDIM 2048
#define TSEQ 4096
#define NR   8192   // 4*H rows of the fused gate matrix

__device__ __forceinline__ float sigmoidf_(float x) { return 1.0f / (1.0f + __expf(-x)); }
__device__ __forceinline__ float tanhf_(float x)    { return 1.0f - 2.0f / (1.0f + __expf(2.0f * x)); }

// Bank-swizzle for the LDS h-stage: 16B groups, low4 of group idx XOR'd with
// bits [7:4] -> reads at fixed i across cc spread over banks (2-4 way max).
__device__ __forceinline__ int swz(int g) { return (g & ~15) | ((g ^ (g >> 4)) & 15); }

// ---------------------------------------------------------------------------
// GEMM: Zx[t][j] = sum_k X[t][k] * w{g}[j&2047][2048+k],  g = j>>11
// M=4096(T) x N=8192(4H) x K=2048(F), fp16 MFMA 16x16x32, 128x128 tile.
// ---------------------------------------------------------------------------
__global__ __launch_bounds__(256) void gemm_zx(
    const float* __restrict__ X,
    const float* __restrict__ wfp, const float* __restrict__ wip,
    const float* __restrict__ wcp, const float* __restrict__ wop,
    _Float16* __restrict__ Zx)
{
    __shared__ __align__(16) _Float16 As[128 * 32];
    __shared__ __align__(16) _Float16 Bs[128 * 32];
    const int tid  = threadIdx.x;
    const int lane = tid & 63;
    const int wv   = tid >> 6;
    const int bm   = blockIdx.x & 31;   // 32 M-tiles
    const int bn   = blockIdx.x >> 5;   // 64 N-tiles
    const int m0 = bm * 128, n0 = bn * 128;
    const int g = n0 >> 11;             // 128-row tile never crosses a gate boundary
    const float* wsrc = (g == 0) ? wfp : (g == 1) ? wip : (g == 2) ? wcp : wop;
    const int nr0 = n0 & 2047;

    f4 acc[4][4];
    #pragma unroll
    for (int i = 0; i < 4; ++i)
        #pragma unroll
        for (int j = 0; j < 4; ++j) acc[i][j] = (f4){0.f, 0.f, 0.f, 0.f};

    const int wm = (wv >> 1) * 64, wn = (wv & 1) * 64;
    const int fr = lane & 15, kg = lane >> 4;

    for (int k0 = 0; k0 < FDIM; k0 += 32) {
        __syncthreads();
        #pragma unroll
        for (int r = 0; r < 2; ++r) {
            const int row = r * 64 + (tid >> 2);
            const int col = (tid & 3) * 8;
            const float* ax = &X[(size_t)(m0 + row) * FDIM + k0 + col];
            f4 a0 = *(const f4*)ax, a1 = *(const f4*)(ax + 4);
            h8 av = { (_Float16)a0[0], (_Float16)a0[1], (_Float16)a0[2], (_Float16)a0[3],
                      (_Float16)a1[0], (_Float16)a1[1], (_Float16)a1[2], (_Float16)a1[3] };
            *(h8*)&As[row * 32 + col] = av;
            const float* bx = &wsrc[(size_t)(nr0 + row) * 4096 + 2048 + k0 + col];
            f4 b0 = *(const f4*)bx, b1 = *(const f4*)(bx + 4);
            h8 bv = { (_Float16)b0[0], (_Float16)b0[1], (_Float16)b0[2], (_Float16)b0[3],
                      (_Float16)b1[0], (_Float16)b1[1], (_Float16)b1[2], (_Float16)b1[3] };
            *(h8*)&Bs[row * 32 + col] = bv;
        }
        __syncthreads();
        h8 af[4], bf[4];
        #pragma unroll
        for (int i = 0; i < 4; ++i) af[i] = *(const h8*)&As[(wm + i * 16 + fr) * 32 + kg * 8];
        #pragma unroll
        for (int j = 0; j < 4; ++j) bf[j] = *(const h8*)&Bs[(wn + j * 16 + fr) * 32 + kg * 8];
        #pragma unroll
        for (int i = 0; i < 4; ++i)
            #pragma unroll
            for (int j = 0; j < 4; ++j)
                acc[i][j] = __builtin_amdgcn_mfma_f32_16x16x32_f16(af[i], bf[j], acc[i][j], 0, 0, 0);
    }
    // C/D layout: col = lane&15 (N), row = (lane>>4)*4 + q (M)   [m89/m91]
    #pragma unroll
    for (int i = 0; i < 4; ++i)
        #pragma unroll
        for (int j = 0; j < 4; ++j)
            #pragma unroll
            for (int q = 0; q < 4; ++q) {
                const int row = m0 + wm + i * 16 + (lane >> 4) * 4 + q;
                const int col = n0 + wn + j * 16 + (lane & 15);
                Zx[(size_t)row * NR + col] = (_Float16)acc[i][j][q];
            }
}

// ---------------------------------------------------------------------------
// Persistent recurrent kernel, fence-free tag-in-word messaging (R4 protocol,
// hardware-verified): hword has 2 slots x 2048 u32; word j of slot (t&1) =
// (t<<16) | fp16bits(h_t[j]). Producers store with sc0 sc1 (coherence point);
// consumers poll their own 8 words with sc0 sc1 loads until tag==t. The
// tag-poll IS the grid barrier (2-slot ring safety: a producer reaches tag
// t+2 on a slot only after every WG consumed tag t). hword is memset to 0
// per launch: slot0 = (tag0, h=0) == correct h_0, no cross-replay aliasing.
// NEW vs R4: weights live in VGPRs (each thread's static 4x64 slice = 128
// VGPRs) instead of LDS -> no 128KiB/step LDS sweep, no weight bank conflicts.
// ---------------------------------------------------------------------------
__global__ __launch_bounds__(256, 1) void lstm_rec(
    const float* __restrict__ wfp, const float* __restrict__ wip,
    const float* __restrict__ wcp, const float* __restrict__ wop,
    const float* __restrict__ bfv, const float* __restrict__ biv,
    const float* __restrict__ bcv, const float* __restrict__ bov,
    const _Float16* __restrict__ Zx,
    u32* __restrict__ hword,          // 2 * 2048 tagged words
    float* __restrict__ hfin)         // 2048 fp32
{
    __shared__ __align__(16) u32 stage[HDIM];  // 8 KiB staged h words
    __shared__ float z_lds[32];
    __shared__ float c_lds[8];

    const int tid = threadIdx.x;
    const int w   = blockIdx.x;
    const int rg  = tid >> 5, cc = tid & 31;

    // ---- one-time: this thread's weight slice into VGPRs (static indexing) ----
    // rows rl = rg*4+q (gate rl>>3, elem rl&7), cols cc*64 + i*8 .. +8
    h8 wreg[4][8];
    #pragma unroll
    for (int q = 0; q < 4; ++q) {
        const int rl = rg * 4 + q;
        const int gg = rl >> 3, r8 = rl & 7;
        const float* src = ((gg == 0) ? wfp : (gg == 1) ? wip : (gg == 2) ? wcp : wop)
                           + (size_t)(8 * w + r8) * 4096 + cc * 64;
        #pragma unroll
        for (int i = 0; i < 8; ++i) {
            f4 a0 = *(const f4*)(src + i * 8);
            f4 a1 = *(const f4*)(src + i * 8 + 4);
            wreg[q][i] = (h8){ (_Float16)a0[0], (_Float16)a0[1], (_Float16)a0[2], (_Float16)a0[3],
                               (_Float16)a1[0], (_Float16)a1[1], (_Float16)a1[2], (_Float16)a1[3] };
        }
    }
    float bias0 = 0.f, bias1 = 0.f, bias2 = 0.f, bias3 = 0.f;
    if (tid < 8) {
        c_lds[tid] = 0.0f;
        bias0 = bfv[8 * w + tid]; bias1 = biv[8 * w + tid];
        bias2 = bcv[8 * w + tid]; bias3 = bov[8 * w + tid];
    }
    __syncthreads();   // c_lds ready (WG-local; no grid barrier needed)

    #pragma unroll 1
    for (int t = 0; t < TSEQ; ++t) {
        float zx0 = 0.f, zx1 = 0.f, zx2 = 0.f, zx3 = 0.f;
        if (tid < 8) {   // x-projection prefetch (plain loads, L2-warm stream)
            const _Float16* zp = Zx + (size_t)t * NR + 8 * w + tid;
            zx0 = (float)zp[0]; zx1 = (float)zp[2048];
            zx2 = (float)zp[4096]; zx3 = (float)zp[6144];
        }

        // ---- poll own 8 tagged words of h_t (slot t&1) at coherence point ----
        const u32* p = hword + (size_t)(t & 1) * HDIM + (size_t)tid * 8;
        const u32 texp = (u32)t << 16;
        u32x4 A, B;
        for (;;) {
            asm volatile(
                "global_load_dwordx4 %0, %2, off sc0 sc1\n\t"
                "global_load_dwordx4 %1, %2, off offset:16 sc0 sc1\n\t"
                "s_waitcnt vmcnt(0)"
                : "=&v"(A), "=&v"(B) : "v"(p) : "memory");
            const u32 bad = ((A.x ^ texp) | (A.y ^ texp) | (A.z ^ texp) | (A.w ^ texp) |
                             (B.x ^ texp) | (B.y ^ texp) | (B.z ^ texp) | (B.w ^ texp))
                            & 0xFFFF0000u;
            if (!bad) break;
            __builtin_amdgcn_s_sleep(1);
        }
        // stage the 8 fresh words (2 swizzled 16B groups) for WG-wide reuse
        *(u32x4*)&stage[swz(tid * 2) * 4]     = A;
        *(u32x4*)&stage[swz(tid * 2 + 1) * 4] = B;
        __syncthreads();

        // ---- dot: 4 rows x 64 cols per thread, weights in VGPRs ----
        float acc[4] = {0.f, 0.f, 0.f, 0.f};
        #pragma unroll
        for (int i = 0; i < 8; ++i) {
            u32x4 ga = *(const u32x4*)&stage[swz(cc * 16 + 2 * i) * 4];
            u32x4 gb = *(const u32x4*)&stage[swz(cc * 16 + 2 * i + 1) * 4];
            const h2 h0  = __builtin_bit_cast(h2, (u32)((ga.x & 0xffffu) | (ga.y << 16)));
            const h2 h1  = __builtin_bit_cast(h2, (u32)((ga.z & 0xffffu) | (ga.w << 16)));
            const h2 h2v = __builtin_bit_cast(h2, (u32)((gb.x & 0xffffu) | (gb.y << 16)));
            const h2 h3  = __builtin_bit_cast(h2, (u32)((gb.z & 0xffffu) | (gb.w << 16)));
            #pragma unroll
            for (int q = 0; q < 4; ++q) {
                const h8 wv8 = wreg[q][i];
                acc[q] = __builtin_amdgcn_fdot2((h2){wv8[0], wv8[1]}, h0,  acc[q], false);
                acc[q] = __builtin_amdgcn_fdot2((h2){wv8[2], wv8[3]}, h1,  acc[q], false);
                acc[q] = __builtin_amdgcn_fdot2((h2){wv8[4], wv8[5]}, h2v, acc[q], false);
                acc[q] = __builtin_amdgcn_fdot2((h2){wv8[6], wv8[7]}, h3,  acc[q], false);
            }
        }
        // reduce across the 32 col-chunk lanes (stays within 32-lane halves)
        #pragma unroll
        for (int m = 16; m >= 1; m >>= 1) {
            #pragma unroll
            for (int q = 0; q < 4; ++q) acc[q] += __shfl_xor(acc[q], m, 64);
        }
        if (cc == 0) {
            #pragma unroll
            for (int q = 0; q < 4; ++q) z_lds[rg * 4 + q] = acc[q];
        }
        __syncthreads();
        if (tid < 8) {   // finalize 8 h-elements; publish tagged words for t+1
            const float zf = z_lds[tid]      + zx0 + bias0;
            const float zi = z_lds[8 + tid]  + zx1 + bias1;
            const float zc = z_lds[16 + tid] + zx2 + bias2;
            const float zo = z_lds[24 + tid] + zx3 + bias3;
            const float f  = sigmoidf_(zf);
            const float i_ = sigmoidf_(zi);
            const float g_ = tanhf_(zc);
            const float o  = sigmoidf_(zo);
            const float cn = f * c_lds[tid] + i_ * g_;
            c_lds[tid] = cn;
            const float hn = o * tanhf_(cn);
            const unsigned short hb =
                __builtin_bit_cast(unsigned short, (_Float16)hn);
            const u32 word = ((u32)(t + 1) << 16) | (u32)hb;
            u32* op = hword + (size_t)((t + 1) & 1) * HDIM + 8 * w + tid;
            asm volatile("global_store_dword %0, %1, off sc0 sc1"
                         :: "v"(op), "v"(word) : "memory");
            if (t == TSEQ - 1) hfin[8 * w + tid] = hn;
        }
    }
}

// ---------------------------------------------------------------------------
// y[row] = by[row] + wy[row,:] . hfin
// ---------------------------------------------------------------------------
__global__ __launch_bounds__(256) void proj(
    const float* __restrict__ wy, const float* __restrict__ byv,
    const float* __restrict__ hfin, float* __restrict__ y)
{
    const int row = blockIdx.x;
    const float* wr = wy + (size_t)row * HDIM;
    float s = 0.f;
    for (int k = threadIdx.x * 4; k < HDIM; k += 256 * 4) {
        f4 wv = *(const f4*)&wr[k];
        f4 hv = *(const f4*)&hfin[k];
        s = fmaf(wv[0], hv[0], fmaf(wv[1], hv[1], fmaf(wv[2], hv[2], fmaf(wv[3], hv[3], s))));
    }
    #pragma unroll
    for (int m = 32; m >= 1; m >>= 1) s += __shfl_xor(s, m, 64);
    __shared__ float red[4];
    if ((threadIdx.x & 63) == 0) red[threadIdx.x >> 6] = s;
    __syncthreads();
    if (threadIdx.x == 0) y[row] = red[0] + red[1] + red[2] + red[3] + byv[row];
}

// ---------------------------------------------------------------------------
extern "C" void kernel_launch(void* const* d_in, const int* in_sizes, int n_in,
                              void* d_out, int out_size, void* d_ws, size_t ws_size,
                              hipStream_t stream)
{
    (void)in_sizes; (void)n_in; (void)out_size;
    const float* X   = (const float*)d_in[0];
    const float* wfp = (const float*)d_in[1];
    const float* bfv = (const float*)d_in[2];
    const float* wip = (const float*)d_in[3];
    const float* biv = (const float*)d_in[4];
    const float* wcp = (const float*)d_in[5];
    const float* bcv = (const float*)d_in[6];
    const float* wop = (const float*)d_in[7];
    const float* bov = (const float*)d_in[8];
    const float* wy  = (const float*)d_in[9];
    const float* byv = (const float*)d_in[10];
    float* y = (float*)d_out;

    char* ws = (char*)d_ws;
    const size_t need = ((size_t)64 << 20) + ((size_t)64 << 10);
    if (ws_size < need) return;  // fail visibly rather than corrupt

    _Float16* Zx  = (_Float16*)ws;                                   // 64 MiB
    u32* hword    = (u32*)(ws + ((size_t)64 << 20));                 // 16 KiB
    float* hfin   = (float*)(ws + ((size_t)64 << 20) + (16 << 10));  // 8 KiB

    // slot0 = (tag 0, h=0) == correct h_0; also kills cross-replay tag aliasing
    (void)hipMemsetAsync(hword, 0, 2 * HDIM * sizeof(u32), stream);
    gemm_zx<<<dim3(2048), dim3(256), 0, stream>>>(X, wfp, wip, wcp, wop, Zx);
    lstm_rec<<<dim3(256), dim3(256), 0, stream>>>(wfp, wip, wcp, wop,
                                                  bfv, biv, bcv, bov,
                                                  Zx, hword, hfin);
    proj<<<dim3(2048), dim3(256), 0, stream>>>(wy, byv, hfin, y);
}

// Round 7
// 9977.565 us; speedup vs baseline: 6.3761x; 1.2092x over previous
//
#include <hip/hip_runtime.h>
#include <hip/hip_fp16.h>

typedef _Float16 h8 __attribute__((ext_vector_type(8)));
typedef _Float16 h2 __attribute__((ext_vector_type(2)));
typedef float    f4 __attribute__((ext_vector_type(4)));
typedef unsigned int u32;
typedef u32 u32x4 __attribute__((ext_vector_type(4)));

#define HDIM 2048
#define FDIM 2048
#define TSEQ 4096
#define NR   8192   // 4*H rows of the fused gate matrix

__device__ __forceinline__ float sigmoidf_(float x) { return 1.0f / (1.0f + __expf(-x)); }
__device__ __forceinline__ float tanhf_(float x)    { return 1.0f - 2.0f / (1.0f + __expf(2.0f * x)); }

// Bank-swizzle for the LDS h-stage: 16B groups, low4 of group idx XOR'd with
// bits [7:4] -> reads at fixed i across cc spread over banks (2-4 way max).
__device__ __forceinline__ int swz(int g) { return (g & ~15) | ((g ^ (g >> 4)) & 15); }

// ---------------------------------------------------------------------------
// GEMM: Zx[t][j] = sum_k X[t][k] * w{g}[j&2047][2048+k],  g = j>>11
// M=4096(T) x N=8192(4H) x K=2048(F), fp16 MFMA 16x16x32, 128x128 tile.
// ---------------------------------------------------------------------------
__global__ __launch_bounds__(256) void gemm_zx(
    const float* __restrict__ X,
    const float* __restrict__ wfp, const float* __restrict__ wip,
    const float* __restrict__ wcp, const float* __restrict__ wop,
    _Float16* __restrict__ Zx)
{
    __shared__ __align__(16) _Float16 As[128 * 32];
    __shared__ __align__(16) _Float16 Bs[128 * 32];
    const int tid  = threadIdx.x;
    const int lane = tid & 63;
    const int wv   = tid >> 6;
    const int bm   = blockIdx.x & 31;   // 32 M-tiles
    const int bn   = blockIdx.x >> 5;   // 64 N-tiles
    const int m0 = bm * 128, n0 = bn * 128;
    const int g = n0 >> 11;             // 128-row tile never crosses a gate boundary
    const float* wsrc = (g == 0) ? wfp : (g == 1) ? wip : (g == 2) ? wcp : wop;
    const int nr0 = n0 & 2047;

    f4 acc[4][4];
    #pragma unroll
    for (int i = 0; i < 4; ++i)
        #pragma unroll
        for (int j = 0; j < 4; ++j) acc[i][j] = (f4){0.f, 0.f, 0.f, 0.f};

    const int wm = (wv >> 1) * 64, wn = (wv & 1) * 64;
    const int fr = lane & 15, kg = lane >> 4;

    for (int k0 = 0; k0 < FDIM; k0 += 32) {
        __syncthreads();
        #pragma unroll
        for (int r = 0; r < 2; ++r) {
            const int row = r * 64 + (tid >> 2);
            const int col = (tid & 3) * 8;
            const float* ax = &X[(size_t)(m0 + row) * FDIM + k0 + col];
            f4 a0 = *(const f4*)ax, a1 = *(const f4*)(ax + 4);
            h8 av = { (_Float16)a0[0], (_Float16)a0[1], (_Float16)a0[2], (_Float16)a0[3],
                      (_Float16)a1[0], (_Float16)a1[1], (_Float16)a1[2], (_Float16)a1[3] };
            *(h8*)&As[row * 32 + col] = av;
            const float* bx = &wsrc[(size_t)(nr0 + row) * 4096 + 2048 + k0 + col];
            f4 b0 = *(const f4*)bx, b1 = *(const f4*)(bx + 4);
            h8 bv = { (_Float16)b0[0], (_Float16)b0[1], (_Float16)b0[2], (_Float16)b0[3],
                      (_Float16)b1[0], (_Float16)b1[1], (_Float16)b1[2], (_Float16)b1[3] };
            *(h8*)&Bs[row * 32 + col] = bv;
        }
        __syncthreads();
        h8 af[4], bf[4];
        #pragma unroll
        for (int i = 0; i < 4; ++i) af[i] = *(const h8*)&As[(wm + i * 16 + fr) * 32 + kg * 8];
        #pragma unroll
        for (int j = 0; j < 4; ++j) bf[j] = *(const h8*)&Bs[(wn + j * 16 + fr) * 32 + kg * 8];
        #pragma unroll
        for (int i = 0; i < 4; ++i)
            #pragma unroll
            for (int j = 0; j < 4; ++j)
                acc[i][j] = __builtin_amdgcn_mfma_f32_16x16x32_f16(af[i], bf[j], acc[i][j], 0, 0, 0);
    }
    // C/D layout: col = lane&15 (N), row = (lane>>4)*4 + q (M)   [m89/m91]
    #pragma unroll
    for (int i = 0; i < 4; ++i)
        #pragma unroll
        for (int j = 0; j < 4; ++j)
            #pragma unroll
            for (int q = 0; q < 4; ++q) {
                const int row = m0 + wm + i * 16 + (lane >> 4) * 4 + q;
                const int col = n0 + wn + j * 16 + (lane & 15);
                Zx[(size_t)row * NR + col] = (_Float16)acc[i][j][q];
            }
}

// ---------------------------------------------------------------------------
// Persistent recurrent kernel, fence-free tag-in-word messaging (R4/R6
// protocol): hword has 2 slots x 2048 u32; word j of slot (t&1) =
// (t<<16) | fp16bits(h_t[j]). Producers store with sc0 sc1; consumers
// verify tags before use. Discovery is split from transfer:
//   Phase A (wave 0): poll 4B sentinel words (one per producer WG's 32B
//     block) -> grid sweep 64KB instead of 2MB, no L3 queue build-up.
//   Phase B (all threads): ONE bulk 8KB load + full tag verify (exactly
//     the R6 loop, so correctness never rests on sentinel=>block-visible;
//     stale non-sentinel words just re-poll, rare).
// Ring safety unchanged: producer reaches tag t+2 on a slot only after all
// WGs consumed tag t. hword memset per launch: slot0=(tag0,h=0)==h_0.
// Weights in VGPRs (static 4x64 slice/thread).
// ---------------------------------------------------------------------------
__global__ __launch_bounds__(256, 1) void lstm_rec(
    const float* __restrict__ wfp, const float* __restrict__ wip,
    const float* __restrict__ wcp, const float* __restrict__ wop,
    const float* __restrict__ bfv, const float* __restrict__ biv,
    const float* __restrict__ bcv, const float* __restrict__ bov,
    const _Float16* __restrict__ Zx,
    u32* __restrict__ hword,          // 2 * 2048 tagged words
    float* __restrict__ hfin)         // 2048 fp32
{
    __shared__ __align__(16) u32 stage[HDIM];  // 8 KiB staged h words
    __shared__ float z_lds[32];
    __shared__ float c_lds[8];

    const int tid = threadIdx.x;
    const int w   = blockIdx.x;
    const int rg  = tid >> 5, cc = tid & 31;

    // ---- one-time: this thread's weight slice into VGPRs (static indexing) ----
    // rows rl = rg*4+q (gate rl>>3, elem rl&7), cols cc*64 + i*8 .. +8
    h8 wreg[4][8];
    #pragma unroll
    for (int q = 0; q < 4; ++q) {
        const int rl = rg * 4 + q;
        const int gg = rl >> 3, r8 = rl & 7;
        const float* src = ((gg == 0) ? wfp : (gg == 1) ? wip : (gg == 2) ? wcp : wop)
                           + (size_t)(8 * w + r8) * 4096 + cc * 64;
        #pragma unroll
        for (int i = 0; i < 8; ++i) {
            f4 a0 = *(const f4*)(src + i * 8);
            f4 a1 = *(const f4*)(src + i * 8 + 4);
            wreg[q][i] = (h8){ (_Float16)a0[0], (_Float16)a0[1], (_Float16)a0[2], (_Float16)a0[3],
                               (_Float16)a1[0], (_Float16)a1[1], (_Float16)a1[2], (_Float16)a1[3] };
        }
    }
    float bias0 = 0.f, bias1 = 0.f, bias2 = 0.f, bias3 = 0.f;
    if (tid < 8) {
        c_lds[tid] = 0.0f;
        bias0 = bfv[8 * w + tid]; bias1 = biv[8 * w + tid];
        bias2 = bcv[8 * w + tid]; bias3 = bov[8 * w + tid];
    }
    __syncthreads();   // c_lds ready (WG-local; no grid barrier needed)

    #pragma unroll 1
    for (int t = 0; t < TSEQ; ++t) {
        float zx0 = 0.f, zx1 = 0.f, zx2 = 0.f, zx3 = 0.f;
        if (tid < 8) {   // x-projection prefetch (plain loads, L2-warm stream)
            const _Float16* zp = Zx + (size_t)t * NR + 8 * w + tid;
            zx0 = (float)zp[0]; zx1 = (float)zp[2048];
            zx2 = (float)zp[4096]; zx3 = (float)zp[6144];
        }

        const u32 texp = (u32)t << 16;
        const size_t slotbase = (size_t)(t & 1) * HDIM;

        // ---- Phase A: wave 0 polls 4B sentinels (one per producer WG) ----
        if (tid < 64) {
            const u32* sp = hword + slotbase + (size_t)tid * 32;  // producers 4*tid..+3
            u32 s0, s1, s2, s3;
            for (;;) {
                asm volatile(
                    "global_load_dword %0, %4, off sc0 sc1\n\t"
                    "global_load_dword %1, %4, off offset:32 sc0 sc1\n\t"
                    "global_load_dword %2, %4, off offset:64 sc0 sc1\n\t"
                    "global_load_dword %3, %4, off offset:96 sc0 sc1\n\t"
                    "s_waitcnt vmcnt(0)"
                    : "=&v"(s0), "=&v"(s1), "=&v"(s2), "=&v"(s3)
                    : "v"(sp) : "memory");
                const u32 bad = ((s0 ^ texp) | (s1 ^ texp) | (s2 ^ texp) | (s3 ^ texp))
                                & 0xFFFF0000u;
                if (!bad) break;
                __builtin_amdgcn_s_sleep(2);
            }
        }
        __syncthreads();   // all data (sentinel-wise) published at L3

        // ---- Phase B: one-shot bulk fetch + full tag verify (R6 loop) ----
        const u32* p = hword + slotbase + (size_t)tid * 8;
        u32x4 A, B;
        for (;;) {
            asm volatile(
                "global_load_dwordx4 %0, %2, off sc0 sc1\n\t"
                "global_load_dwordx4 %1, %2, off offset:16 sc0 sc1\n\t"
                "s_waitcnt vmcnt(0)"
                : "=&v"(A), "=&v"(B) : "v"(p) : "memory");
            const u32 bad = ((A.x ^ texp) | (A.y ^ texp) | (A.z ^ texp) | (A.w ^ texp) |
                             (B.x ^ texp) | (B.y ^ texp) | (B.z ^ texp) | (B.w ^ texp))
                            & 0xFFFF0000u;
            if (!bad) break;
            __builtin_amdgcn_s_sleep(1);
        }
        // stage the 8 fresh words (2 swizzled 16B groups) for WG-wide reuse
        *(u32x4*)&stage[swz(tid * 2) * 4]     = A;
        *(u32x4*)&stage[swz(tid * 2 + 1) * 4] = B;
        __syncthreads();

        // ---- dot: 4 rows x 64 cols per thread, weights in VGPRs ----
        float acc[4] = {0.f, 0.f, 0.f, 0.f};
        #pragma unroll
        for (int i = 0; i < 8; ++i) {
            u32x4 ga = *(const u32x4*)&stage[swz(cc * 16 + 2 * i) * 4];
            u32x4 gb = *(const u32x4*)&stage[swz(cc * 16 + 2 * i + 1) * 4];
            const h2 h0  = __builtin_bit_cast(h2, (u32)((ga.x & 0xffffu) | (ga.y << 16)));
            const h2 h1  = __builtin_bit_cast(h2, (u32)((ga.z & 0xffffu) | (ga.w << 16)));
            const h2 h2v = __builtin_bit_cast(h2, (u32)((gb.x & 0xffffu) | (gb.y << 16)));
            const h2 h3  = __builtin_bit_cast(h2, (u32)((gb.z & 0xffffu) | (gb.w << 16)));
            #pragma unroll
            for (int q = 0; q < 4; ++q) {
                const h8 wv8 = wreg[q][i];
                acc[q] = __builtin_amdgcn_fdot2((h2){wv8[0], wv8[1]}, h0,  acc[q], false);
                acc[q] = __builtin_amdgcn_fdot2((h2){wv8[2], wv8[3]}, h1,  acc[q], false);
                acc[q] = __builtin_amdgcn_fdot2((h2){wv8[4], wv8[5]}, h2v, acc[q], false);
                acc[q] = __builtin_amdgcn_fdot2((h2){wv8[6], wv8[7]}, h3,  acc[q], false);
            }
        }
        // reduce across the 32 col-chunk lanes (stays within 32-lane halves)
        #pragma unroll
        for (int m = 16; m >= 1; m >>= 1) {
            #pragma unroll
            for (int q = 0; q < 4; ++q) acc[q] += __shfl_xor(acc[q], m, 64);
        }
        if (cc == 0) {
            #pragma unroll
            for (int q = 0; q < 4; ++q) z_lds[rg * 4 + q] = acc[q];
        }
        __syncthreads();
        if (tid < 8) {   // finalize 8 h-elements; publish tagged words for t+1
            const float zf = z_lds[tid]      + zx0 + bias0;
            const float zi = z_lds[8 + tid]  + zx1 + bias1;
            const float zc = z_lds[16 + tid] + zx2 + bias2;
            const float zo = z_lds[24 + tid] + zx3 + bias3;
            const float f  = sigmoidf_(zf);
            const float i_ = sigmoidf_(zi);
            const float g_ = tanhf_(zc);
            const float o  = sigmoidf_(zo);
            const float cn = f * c_lds[tid] + i_ * g_;
            c_lds[tid] = cn;
            const float hn = o * tanhf_(cn);
            const unsigned short hb =
                __builtin_bit_cast(unsigned short, (_Float16)hn);
            const u32 word = ((u32)(t + 1) << 16) | (u32)hb;
            u32* op = hword + (size_t)((t + 1) & 1) * HDIM + 8 * w + tid;
            asm volatile("global_store_dword %0, %1, off sc0 sc1"
                         :: "v"(op), "v"(word) : "memory");
            if (t == TSEQ - 1) hfin[8 * w + tid] = hn;
        }
    }
}

// ---------------------------------------------------------------------------
// y[row] = by[row] + wy[row,:] . hfin
// ---------------------------------------------------------------------------
__global__ __launch_bounds__(256) void proj(
    const float* __restrict__ wy, const float* __restrict__ byv,
    const float* __restrict__ hfin, float* __restrict__ y)
{
    const int row = blockIdx.x;
    const float* wr = wy + (size_t)row * HDIM;
    float s = 0.f;
    for (int k = threadIdx.x * 4; k < HDIM; k += 256 * 4) {
        f4 wv = *(const f4*)&wr[k];
        f4 hv = *(const f4*)&hfin[k];
        s = fmaf(wv[0], hv[0], fmaf(wv[1], hv[1], fmaf(wv[2], hv[2], fmaf(wv[3], hv[3], s))));
    }
    #pragma unroll
    for (int m = 32; m >= 1; m >>= 1) s += __shfl_xor(s, m, 64);
    __shared__ float red[4];
    if ((threadIdx.x & 63) == 0) red[threadIdx.x >> 6] = s;
    __syncthreads();
    if (threadIdx.x == 0) y[row] = red[0] + red[1] + red[2] + red[3] + byv[row];
}

// ---------------------------------------------------------------------------
extern "C" void kernel_launch(void* const* d_in, const int* in_sizes, int n_in,
                              void* d_out, int out_size, void* d_ws, size_t ws_size,
                              hipStream_t stream)
{
    (void)in_sizes; (void)n_in; (void)out_size;
    const float* X   = (const float*)d_in[0];
    const float* wfp = (const float*)d_in[1];
    const float* bfv = (const float*)d_in[2];
    const float* wip = (const float*)d_in[3];
    const float* biv = (const float*)d_in[4];
    const float* wcp = (const float*)d_in[5];
    const float* bcv = (const float*)d_in[6];
    const float* wop = (const float*)d_in[7];
    const float* bov = (const float*)d_in[8];
    const float* wy  = (const float*)d_in[9];
    const float* byv = (const float*)d_in[10];
    float* y = (float*)d_out;

    char* ws = (char*)d_ws;
    const size_t need = ((size_t)64 << 20) + ((size_t)64 << 10);
    if (ws_size < need) return;  // fail visibly rather than corrupt

    _Float16* Zx  = (_Float16*)ws;                                   // 64 MiB
    u32* hword    = (u32*)(ws + ((size_t)64 << 20));                 // 16 KiB
    float* hfin   = (float*)(ws + ((size_t)64 << 20) + (16 << 10));  // 8 KiB

    // slot0 = (tag 0, h=0) == correct h_0; also kills cross-replay tag aliasing
    (void)hipMemsetAsync(hword, 0, 2 * HDIM * sizeof(u32), stream);
    gemm_zx<<<dim3(2048), dim3(256), 0, stream>>>(X, wfp, wip, wcp, wop, Zx);
    lstm_rec<<<dim3(256), dim3(256), 0, stream>>>(wfp, wip, wcp, wop,
                                                  bfv, biv, bcv, bov,
                                                  Zx, hword, hfin);
    proj<<<dim3(2048), dim3(256), 0, stream>>>(wy, byv, hfin, y);
}

// Round 8
// 9837.631 us; speedup vs baseline: 6.4668x; 1.0142x over previous
//
#include <hip/hip_runtime.h>
#include <hip/hip_fp16.h>

typedef _Float16 h8 __attribute__((ext_vector_type(8)));
typedef _Float16 h2 __attribute__((ext_vector_type(2)));
typedef float    f4 __attribute__((ext_vector_type(4)));
typedef unsigned int u32;
typedef u32 u32x4 __attribute__((ext_vector_type(4)));

#define HDIM 2048
#define FDIM 2048
#define TSEQ 4096
#define NR   8192   // 4*H rows of the fused gate matrix

__device__ __forceinline__ float sigmoidf_(float x) { return 1.0f / (1.0f + __expf(-x)); }
__device__ __forceinline__ float tanhf_(float x)    { return 1.0f - 2.0f / (1.0f + __expf(2.0f * x)); }

// Bank-swizzle for the LDS h-stage: 16B groups, low4 of group idx XOR'd with
// bits [7:4] -> reads at fixed i across cc spread over banks (2-4 way max).
__device__ __forceinline__ int swz(int g) { return (g & ~15) | ((g ^ (g >> 4)) & 15); }

// ---------------------------------------------------------------------------
// GEMM: Zx[t][j] = sum_k X[t][k] * w{g}[j&2047][2048+k],  g = j>>11
// M=4096(T) x N=8192(4H) x K=2048(F), fp16 MFMA 16x16x32, 128x128 tile.
// ---------------------------------------------------------------------------
__global__ __launch_bounds__(256) void gemm_zx(
    const float* __restrict__ X,
    const float* __restrict__ wfp, const float* __restrict__ wip,
    const float* __restrict__ wcp, const float* __restrict__ wop,
    _Float16* __restrict__ Zx)
{
    __shared__ __align__(16) _Float16 As[128 * 32];
    __shared__ __align__(16) _Float16 Bs[128 * 32];
    const int tid  = threadIdx.x;
    const int lane = tid & 63;
    const int wv   = tid >> 6;
    const int bm   = blockIdx.x & 31;   // 32 M-tiles
    const int bn   = blockIdx.x >> 5;   // 64 N-tiles
    const int m0 = bm * 128, n0 = bn * 128;
    const int g = n0 >> 11;             // 128-row tile never crosses a gate boundary
    const float* wsrc = (g == 0) ? wfp : (g == 1) ? wip : (g == 2) ? wcp : wop;
    const int nr0 = n0 & 2047;

    f4 acc[4][4];
    #pragma unroll
    for (int i = 0; i < 4; ++i)
        #pragma unroll
        for (int j = 0; j < 4; ++j) acc[i][j] = (f4){0.f, 0.f, 0.f, 0.f};

    const int wm = (wv >> 1) * 64, wn = (wv & 1) * 64;
    const int fr = lane & 15, kg = lane >> 4;

    for (int k0 = 0; k0 < FDIM; k0 += 32) {
        __syncthreads();
        #pragma unroll
        for (int r = 0; r < 2; ++r) {
            const int row = r * 64 + (tid >> 2);
            const int col = (tid & 3) * 8;
            const float* ax = &X[(size_t)(m0 + row) * FDIM + k0 + col];
            f4 a0 = *(const f4*)ax, a1 = *(const f4*)(ax + 4);
            h8 av = { (_Float16)a0[0], (_Float16)a0[1], (_Float16)a0[2], (_Float16)a0[3],
                      (_Float16)a1[0], (_Float16)a1[1], (_Float16)a1[2], (_Float16)a1[3] };
            *(h8*)&As[row * 32 + col] = av;
            const float* bx = &wsrc[(size_t)(nr0 + row) * 4096 + 2048 + k0 + col];
            f4 b0 = *(const f4*)bx, b1 = *(const f4*)(bx + 4);
            h8 bv = { (_Float16)b0[0], (_Float16)b0[1], (_Float16)b0[2], (_Float16)b0[3],
                      (_Float16)b1[0], (_Float16)b1[1], (_Float16)b1[2], (_Float16)b1[3] };
            *(h8*)&Bs[row * 32 + col] = bv;
        }
        __syncthreads();
        h8 af[4], bf[4];
        #pragma unroll
        for (int i = 0; i < 4; ++i) af[i] = *(const h8*)&As[(wm + i * 16 + fr) * 32 + kg * 8];
        #pragma unroll
        for (int j = 0; j < 4; ++j) bf[j] = *(const h8*)&Bs[(wn + j * 16 + fr) * 32 + kg * 8];
        #pragma unroll
        for (int i = 0; i < 4; ++i)
            #pragma unroll
            for (int j = 0; j < 4; ++j)
                acc[i][j] = __builtin_amdgcn_mfma_f32_16x16x32_f16(af[i], bf[j], acc[i][j], 0, 0, 0);
    }
    // C/D layout: col = lane&15 (N), row = (lane>>4)*4 + q (M)   [m89/m91]
    #pragma unroll
    for (int i = 0; i < 4; ++i)
        #pragma unroll
        for (int j = 0; j < 4; ++j)
            #pragma unroll
            for (int q = 0; q < 4; ++q) {
                const int row = m0 + wm + i * 16 + (lane >> 4) * 4 + q;
                const int col = n0 + wn + j * 16 + (lane & 15);
                Zx[(size_t)row * NR + col] = (_Float16)acc[i][j][q];
            }
}

// ---------------------------------------------------------------------------
// Persistent recurrent kernel, fence-free tag-in-word messaging.
// hword: 2 slots x 2048 u32; word j of slot (t&1) = (t<<16)|fp16bits(h_t[j]).
// NEW vs R7: producers publish via global_atomic_swap sc1 (executes at the
// device coherence point, leaves the line dirty THERE instead of a
// write-through store) -- consumers' sc0 sc1 polls then hit L3, cutting the
// store-visibility leg if plain sc0sc1 stores were streaming past L3.
// Discovery/transfer split unchanged (Phase A sentinels by wave 0, Phase B
// bulk fetch + full tag verify by all threads -- correctness never rests on
// sentinel=>block visibility). Ring safety unchanged. Gate tail now runs on
// 32 lanes (one activation each) + shfl combine; cell state in registers.
// ---------------------------------------------------------------------------
__global__ __launch_bounds__(256, 1) void lstm_rec(
    const float* __restrict__ wfp, const float* __restrict__ wip,
    const float* __restrict__ wcp, const float* __restrict__ wop,
    const float* __restrict__ bfv, const float* __restrict__ biv,
    const float* __restrict__ bcv, const float* __restrict__ bov,
    const _Float16* __restrict__ Zx,
    u32* __restrict__ hword,          // 2 * 2048 tagged words
    float* __restrict__ hfin)         // 2048 fp32
{
    __shared__ __align__(16) u32 stage[HDIM];  // 8 KiB staged h words
    __shared__ float z_lds[32];

    const int tid = threadIdx.x;
    const int w   = blockIdx.x;
    const int rg  = tid >> 5, cc = tid & 31;

    // ---- one-time: this thread's weight slice into VGPRs (static indexing) ----
    // rows rl = rg*4+q (gate rl>>3, elem rl&7), cols cc*64 + i*8 .. +8
    h8 wreg[4][8];
    #pragma unroll
    for (int q = 0; q < 4; ++q) {
        const int rl = rg * 4 + q;
        const int gg = rl >> 3, r8 = rl & 7;
        const float* src = ((gg == 0) ? wfp : (gg == 1) ? wip : (gg == 2) ? wcp : wop)
                           + (size_t)(8 * w + r8) * 4096 + cc * 64;
        #pragma unroll
        for (int i = 0; i < 8; ++i) {
            f4 a0 = *(const f4*)(src + i * 8);
            f4 a1 = *(const f4*)(src + i * 8 + 4);
            wreg[q][i] = (h8){ (_Float16)a0[0], (_Float16)a0[1], (_Float16)a0[2], (_Float16)a0[3],
                               (_Float16)a1[0], (_Float16)a1[1], (_Float16)a1[2], (_Float16)a1[3] };
        }
    }
    // ---- per-lane gate parameters (lanes 0..31: gate = tid>>3, elem = tid&7) ----
    float bias_g = 0.f;
    float c_reg  = 0.f;                       // cell state, valid in lanes 0..7
    const _Float16* zx_ptr = Zx;              // dummy init
    if (tid < 32) {
        const int gg = tid >> 3, e = tid & 7;
        const float* bsrc = (gg == 0) ? bfv : (gg == 1) ? biv : (gg == 2) ? bcv : bov;
        bias_g = bsrc[8 * w + e];
        zx_ptr = Zx + (size_t)gg * 2048 + 8 * w + e;   // + t*NR per step
    }

    #pragma unroll 1
    for (int t = 0; t < TSEQ; ++t) {
        float zx_g = 0.f;
        if (tid < 32) zx_g = (float)zx_ptr[(size_t)t * NR];   // prefetch early

        const u32 texp = (u32)t << 16;
        const size_t slotbase = (size_t)(t & 1) * HDIM;

        // ---- Phase A: wave 0 polls 4B sentinels (one per producer WG) ----
        if (tid < 64) {
            const u32* sp = hword + slotbase + (size_t)tid * 32;  // producers 4*tid..+3
            u32 s0, s1, s2, s3;
            for (;;) {
                asm volatile(
                    "global_load_dword %0, %4, off sc0 sc1\n\t"
                    "global_load_dword %1, %4, off offset:32 sc0 sc1\n\t"
                    "global_load_dword %2, %4, off offset:64 sc0 sc1\n\t"
                    "global_load_dword %3, %4, off offset:96 sc0 sc1\n\t"
                    "s_waitcnt vmcnt(0)"
                    : "=&v"(s0), "=&v"(s1), "=&v"(s2), "=&v"(s3)
                    : "v"(sp) : "memory");
                const u32 bad = ((s0 ^ texp) | (s1 ^ texp) | (s2 ^ texp) | (s3 ^ texp))
                                & 0xFFFF0000u;
                if (!bad) break;
            }
        }
        __syncthreads();   // all data (sentinel-wise) published at L3

        // ---- Phase B: one-shot bulk fetch + full tag verify ----
        const u32* p = hword + slotbase + (size_t)tid * 8;
        u32x4 A, B;
        for (;;) {
            asm volatile(
                "global_load_dwordx4 %0, %2, off sc0 sc1\n\t"
                "global_load_dwordx4 %1, %2, off offset:16 sc0 sc1\n\t"
                "s_waitcnt vmcnt(0)"
                : "=&v"(A), "=&v"(B) : "v"(p) : "memory");
            const u32 bad = ((A.x ^ texp) | (A.y ^ texp) | (A.z ^ texp) | (A.w ^ texp) |
                             (B.x ^ texp) | (B.y ^ texp) | (B.z ^ texp) | (B.w ^ texp))
                            & 0xFFFF0000u;
            if (!bad) break;
            __builtin_amdgcn_s_sleep(1);
        }
        // stage the 8 fresh words (2 swizzled 16B groups) for WG-wide reuse
        *(u32x4*)&stage[swz(tid * 2) * 4]     = A;
        *(u32x4*)&stage[swz(tid * 2 + 1) * 4] = B;
        __syncthreads();

        // ---- dot: 4 rows x 64 cols per thread, weights in VGPRs ----
        float acc[4] = {0.f, 0.f, 0.f, 0.f};
        #pragma unroll
        for (int i = 0; i < 8; ++i) {
            u32x4 ga = *(const u32x4*)&stage[swz(cc * 16 + 2 * i) * 4];
            u32x4 gb = *(const u32x4*)&stage[swz(cc * 16 + 2 * i + 1) * 4];
            const h2 h0  = __builtin_bit_cast(h2, (u32)((ga.x & 0xffffu) | (ga.y << 16)));
            const h2 h1  = __builtin_bit_cast(h2, (u32)((ga.z & 0xffffu) | (ga.w << 16)));
            const h2 h2v = __builtin_bit_cast(h2, (u32)((gb.x & 0xffffu) | (gb.y << 16)));
            const h2 h3  = __builtin_bit_cast(h2, (u32)((gb.z & 0xffffu) | (gb.w << 16)));
            #pragma unroll
            for (int q = 0; q < 4; ++q) {
                const h8 wv8 = wreg[q][i];
                acc[q] = __builtin_amdgcn_fdot2((h2){wv8[0], wv8[1]}, h0,  acc[q], false);
                acc[q] = __builtin_amdgcn_fdot2((h2){wv8[2], wv8[3]}, h1,  acc[q], false);
                acc[q] = __builtin_amdgcn_fdot2((h2){wv8[4], wv8[5]}, h2v, acc[q], false);
                acc[q] = __builtin_amdgcn_fdot2((h2){wv8[6], wv8[7]}, h3,  acc[q], false);
            }
        }
        // reduce across the 32 col-chunk lanes (stays within 32-lane halves)
        #pragma unroll
        for (int m = 16; m >= 1; m >>= 1) {
            #pragma unroll
            for (int q = 0; q < 4; ++q) acc[q] += __shfl_xor(acc[q], m, 64);
        }
        if (cc == 0) {
            #pragma unroll
            for (int q = 0; q < 4; ++q) z_lds[rg * 4 + q] = acc[q];  // idx = gate*8+e
        }
        __syncthreads();

        // ---- gate tail: 32 lanes, one activation each; combine on lanes 0..7 ----
        if (tid < 32) {
            const float zsum = z_lds[tid] + zx_g + bias_g;
            const int gg = tid >> 3;
            const float act = (gg == 2) ? tanhf_(zsum) : sigmoidf_(zsum);
            const int e = tid & 7;
            const float ai = __shfl(act, e + 8, 64);
            const float ag = __shfl(act, e + 16, 64);
            const float ao = __shfl(act, e + 24, 64);
            if (tid < 8) {
                const float cn = act * c_reg + ai * ag;   // act == f gate here
                c_reg = cn;
                const float hn = ao * tanhf_(cn);
                const unsigned short hb =
                    __builtin_bit_cast(unsigned short, (_Float16)hn);
                const u32 word = ((u32)(t + 1) << 16) | (u32)hb;
                u32* op = hword + (size_t)((t + 1) & 1) * HDIM + 8 * w + tid;
                asm volatile("global_atomic_swap %0, %1, off sc1"
                             :: "v"(op), "v"(word) : "memory");
                if (t == TSEQ - 1) hfin[8 * w + tid] = hn;
            }
        }
    }
}

// ---------------------------------------------------------------------------
// y[row] = by[row] + wy[row,:] . hfin
// ---------------------------------------------------------------------------
__global__ __launch_bounds__(256) void proj(
    const float* __restrict__ wy, const float* __restrict__ byv,
    const float* __restrict__ hfin, float* __restrict__ y)
{
    const int row = blockIdx.x;
    const float* wr = wy + (size_t)row * HDIM;
    float s = 0.f;
    for (int k = threadIdx.x * 4; k < HDIM; k += 256 * 4) {
        f4 wv = *(const f4*)&wr[k];
        f4 hv = *(const f4*)&hfin[k];
        s = fmaf(wv[0], hv[0], fmaf(wv[1], hv[1], fmaf(wv[2], hv[2], fmaf(wv[3], hv[3], s))));
    }
    #pragma unroll
    for (int m = 32; m >= 1; m >>= 1) s += __shfl_xor(s, m, 64);
    __shared__ float red[4];
    if ((threadIdx.x & 63) == 0) red[threadIdx.x >> 6] = s;
    __syncthreads();
    if (threadIdx.x == 0) y[row] = red[0] + red[1] + red[2] + red[3] + byv[row];
}

// ---------------------------------------------------------------------------
extern "C" void kernel_launch(void* const* d_in, const int* in_sizes, int n_in,
                              void* d_out, int out_size, void* d_ws, size_t ws_size,
                              hipStream_t stream)
{
    (void)in_sizes; (void)n_in; (void)out_size;
    const float* X   = (const float*)d_in[0];
    const float* wfp = (const float*)d_in[1];
    const float* bfv = (const float*)d_in[2];
    const float* wip = (const float*)d_in[3];
    const float* biv = (const float*)d_in[4];
    const float* wcp = (const float*)d_in[5];
    const float* bcv = (const float*)d_in[6];
    const float* wop = (const float*)d_in[7];
    const float* bov = (const float*)d_in[8];
    const float* wy  = (const float*)d_in[9];
    const float* byv = (const float*)d_in[10];
    float* y = (float*)d_out;

    char* ws = (char*)d_ws;
    const size_t need = ((size_t)64 << 20) + ((size_t)64 << 10);
    if (ws_size < need) return;  // fail visibly rather than corrupt

    _Float16* Zx  = (_Float16*)ws;                                   // 64 MiB
    u32* hword    = (u32*)(ws + ((size_t)64 << 20));                 // 16 KiB
    float* hfin   = (float*)(ws + ((size_t)64 << 20) + (16 << 10));  // 8 KiB

    // slot0 = (tag 0, h=0) == correct h_0; also kills cross-replay tag aliasing
    (void)hipMemsetAsync(hword, 0, 2 * HDIM * sizeof(u32), stream);
    gemm_zx<<<dim3(2048), dim3(256), 0, stream>>>(X, wfp, wip, wcp, wop, Zx);
    lstm_rec<<<dim3(256), dim3(256), 0, stream>>>(wfp, wip, wcp, wop,
                                                  bfv, biv, bcv, bov,
                                                  Zx, hword, hfin);
    proj<<<dim3(2048), dim3(256), 0, stream>>>(wy, byv, hfin, y);
}